// Round 1
// baseline (2280.545 us; speedup 1.0000x reference)
//
#include <hip/hip_runtime.h>

typedef _Float16 half8 __attribute__((ext_vector_type(8)));
typedef _Float16 half4v __attribute__((ext_vector_type(4)));
typedef float f32x4 __attribute__((ext_vector_type(4)));

#define LDH 136   // padded row stride (elements) for h16/agg16: 272B -> +4 bank rotation
#define LDC 72    // padded row stride for C1c/C3c: 144B -> +4 bank rotation

// ---------------- weight prep: fp32 [k][n] -> fp16 [n][k] in d_ws ----------------
// layout (fp16 elements): w1t @0 (256x256), w2t @65536 (128x256),
//                         nw1t @98304 (256x256), nw2t @163840 (128x256)
__global__ void prep_weights(const float* __restrict__ ew1,
                             const float* __restrict__ ew2,
                             const float* __restrict__ nw1,
                             const float* __restrict__ nw2,
                             _Float16* __restrict__ wz) {
  int idx = blockIdx.x * 256 + threadIdx.x;
  if (idx < 65536) {                       // ew1 rows k<256 only (rel rows handled separately)
    int k = idx >> 8, n = idx & 255;
    wz[n * 256 + k] = (_Float16)ew1[idx];
  } else if (idx < 98304) {
    int s = idx - 65536;
    int k = s >> 7, n = s & 127;
    wz[65536 + n * 256 + k] = (_Float16)ew2[s];
  } else if (idx < 163840) {
    int s = idx - 98304;
    int k = s >> 8, n = s & 255;
    wz[98304 + n * 256 + k] = (_Float16)nw1[s];
  } else if (idx < 196608) {
    int s = idx - 163840;
    int k = s >> 7, n = s & 127;
    wz[163840 + n * 256 + k] = (_Float16)nw2[s];
  }
}

// ---------------- fused graph layer: 4 batches per block ----------------
__global__ __launch_bounds__(256, 2)
void fused_graph_layer(const float* __restrict__ h, const float* __restrict__ xy,
                       const int* __restrict__ jmask, const int* __restrict__ eidx,
                       const float* __restrict__ ew1,   // for rel rows 256,257
                       const float* __restrict__ eb1, const float* __restrict__ eb2,
                       const float* __restrict__ nb1, const float* __restrict__ nb2,
                       const float* __restrict__ gamma, const float* __restrict__ beta,
                       const _Float16* __restrict__ wz,
                       float* __restrict__ out) {
  __shared__ _Float16 sh_h16[4 * 17 * LDH];     // 18496 B
  __shared__ _Float16 sh_agg16[4 * 17 * LDH];   // 18496 B
  __shared__ float    sh_S[8704];               // 34816 B: agg32 / C1c / C3c (time-aliased)
  __shared__ float    sh_rel[128 * 2];
  __shared__ float    sh_valid[128];
  __shared__ float    sh_denom[68];
  __shared__ float    sh_hasn[68];
  __shared__ float    sh_maskf[68];
  __shared__ int      sh_edge[64];

  const int tid  = threadIdx.x;
  const int wave = tid >> 6;
  const int lane = tid & 63;
  const int ln   = lane & 15;
  const int quad = lane >> 4;
  const int n0   = blockIdx.x * 4;
  const size_t hbase = (size_t)n0 * (17 * 128);
  const f32x4 vzero = {0.f, 0.f, 0.f, 0.f};

  // ---- stage ----
  if (tid < 64) sh_edge[tid] = eidx[tid];
  if (tid < 68) sh_maskf[tid] = (float)jmask[n0 * 17 + tid];
  for (int i = tid; i < 2176; i += 256) {           // 8704 floats as float4
    const float4 hv = ((const float4*)(h + hbase))[i];
    int q = i << 2;
    int gv = q >> 7, d = q & 127;
    half4v hq = { (_Float16)hv.x, (_Float16)hv.y, (_Float16)hv.z, (_Float16)hv.w };
    *(half4v*)&sh_h16[gv * LDH + d] = hq;
  }
  __syncthreads();
  if (tid < 128) {                                   // rel + edge_valid per (g,e)
    int g = tid >> 5, e = tid & 31;
    int dv = sh_edge[2 * e], sv = sh_edge[2 * e + 1];
    const float* xyb = xy + (size_t)(n0 + g) * 34;
    sh_rel[2 * tid]     = xyb[2 * sv]     - xyb[2 * dv];
    sh_rel[2 * tid + 1] = xyb[2 * sv + 1] - xyb[2 * dv + 1];
    sh_valid[tid] = sh_maskf[g * 17 + dv] * sh_maskf[g * 17 + sv];
  }
  __syncthreads();
  if (tid < 68) {                                    // denom per (g,v)
    int g = tid / 17, v = tid - g * 17;
    float den = 0.f;
    for (int e = 0; e < 32; ++e)
      if (sh_edge[2 * e] == v) den += sh_valid[g * 32 + e];
    sh_denom[tid] = den;
    sh_hasn[tid]  = den > 0.f ? 1.f : 0.f;
  }
  __syncthreads();

  const _Float16* w1t  = wz;
  const _Float16* w2t  = wz + 65536;
  const _Float16* nw1t = wz + 98304;
  const _Float16* nw2t = wz + 163840;
  const float* w1r0 = ew1 + 256 * 256;
  const float* w1r1 = ew1 + 257 * 256;
  _Float16* C1c = (_Float16*)sh_S;                   // 128 x LDC

  // ================= EDGE PHASE: M1=128 rows (g*32+e), 8 m-tiles, 2/wave =========
  int baseT[2], baseS[2];
  #pragma unroll
  for (int mi = 0; mi < 2; ++mi) {
    int R = (2 * wave + mi) * 16 + ln;
    int g = R >> 5, e = R & 31;
    baseT[mi] = (g * 17 + sh_edge[2 * e]) * LDH;
    baseS[mi] = (g * 17 + sh_edge[2 * e + 1]) * LDH;
  }

  f32x4 acc2[2][8];
  #pragma unroll
  for (int i = 0; i < 2; ++i)
    #pragma unroll
    for (int j = 0; j < 8; ++j) acc2[i][j] = vzero;

  for (int nc = 0; nc < 4; ++nc) {
    // GEMM1: hidden chunk [nc*64, nc*64+64)
    f32x4 acc1[2][4];
    #pragma unroll
    for (int i = 0; i < 2; ++i)
      #pragma unroll
      for (int j = 0; j < 4; ++j) acc1[i][j] = vzero;
    #pragma unroll
    for (int ks = 0; ks < 8; ++ks) {
      int k = ks * 32 + quad * 8;
      half8 af[2];
      #pragma unroll
      for (int mi = 0; mi < 2; ++mi) {
        int base = (k < 128) ? (baseT[mi] + k) : (baseS[mi] + k - 128);
        af[mi] = *(const half8*)&sh_h16[base];
      }
      half8 bf[4];
      #pragma unroll
      for (int nt = 0; nt < 4; ++nt)
        bf[nt] = *(const half8*)&w1t[(nc * 64 + nt * 16 + ln) * 256 + k];
      #pragma unroll
      for (int mi = 0; mi < 2; ++mi)
        #pragma unroll
        for (int nt = 0; nt < 4; ++nt)
          acc1[mi][nt] = __builtin_amdgcn_mfma_f32_16x16x32_f16(af[mi], bf[nt], acc1[mi][nt], 0, 0, 0);
    }
    // epilogue1: + eb1 + rel·W1rel, relu, fp16 -> C1c
    #pragma unroll
    for (int nt = 0; nt < 4; ++nt) {
      int J = nc * 64 + nt * 16 + ln;
      float b = eb1[J], r0 = w1r0[J], r1 = w1r1[J];
      #pragma unroll
      for (int mi = 0; mi < 2; ++mi) {
        #pragma unroll
        for (int r = 0; r < 4; ++r) {
          int R = (2 * wave + mi) * 16 + quad * 4 + r;
          float val = acc1[mi][nt][r] + b + sh_rel[2 * R] * r0 + sh_rel[2 * R + 1] * r1;
          val = fmaxf(val, 0.f);
          C1c[R * LDC + nt * 16 + ln] = (_Float16)val;
        }
      }
    }
    __syncthreads();
    // GEMM2 partial-K accumulate
    #pragma unroll
    for (int ks = 0; ks < 2; ++ks) {
      int k = ks * 32 + quad * 8;
      half8 af[2];
      #pragma unroll
      for (int mi = 0; mi < 2; ++mi)
        af[mi] = *(const half8*)&C1c[((2 * wave + mi) * 16 + ln) * LDC + k];
      #pragma unroll
      for (int nt2 = 0; nt2 < 8; ++nt2) {
        half8 bf = *(const half8*)&w2t[(nt2 * 16 + ln) * 256 + nc * 64 + k];
        #pragma unroll
        for (int mi = 0; mi < 2; ++mi)
          acc2[mi][nt2] = __builtin_amdgcn_mfma_f32_16x16x32_f16(af[mi], bf, acc2[mi][nt2], 0, 0, 0);
      }
    }
    __syncthreads();  // before next nc overwrites C1c
  }

  // ---- aggregate messages into agg32 (LDS atomics) ----
  float* agg32 = sh_S;
  for (int i = tid; i < 8704; i += 256) agg32[i] = 0.f;
  __syncthreads();
  #pragma unroll
  for (int nt2 = 0; nt2 < 8; ++nt2) {
    int d = nt2 * 16 + ln;
    float b2 = eb2[d];
    #pragma unroll
    for (int mi = 0; mi < 2; ++mi) {
      #pragma unroll
      for (int r = 0; r < 4; ++r) {
        int R = (2 * wave + mi) * 16 + quad * 4 + r;
        int g = R >> 5, e = R & 31;
        float msg = (acc2[mi][nt2][r] + b2) * sh_valid[R];
        atomicAdd(&agg32[(g * 17 + sh_edge[2 * e]) * 128 + d], msg);
      }
    }
  }
  __syncthreads();
  // divide by max(denom,1), cvt fp16
  for (int i = tid; i < 8704; i += 256) {
    int gv = i >> 7, d = i & 127;
    float den = fmaxf(sh_denom[gv], 1.f);
    sh_agg16[gv * LDH + d] = (_Float16)(agg32[i] / den);
  }
  __syncthreads();

  // ================= NODE PHASE: M2=68 rows (R = g*17+v), 5 m-tiles =============
  _Float16* C3c = (_Float16*)sh_S;                   // 80 x LDC
  const int nmt = (wave == 0) ? 2 : 1;
  int mts[2]; mts[0] = wave; mts[1] = 4;

  f32x4 acc4[2][8];
  #pragma unroll
  for (int i = 0; i < 2; ++i)
    #pragma unroll
    for (int j = 0; j < 8; ++j) acc4[i][j] = vzero;

  for (int nc = 0; nc < 4; ++nc) {
    for (int u = 0; u < nmt; ++u) {
      int mt = mts[u];
      int R = mt * 16 + ln;
      int Rc = R < 68 ? R : 67;
      f32x4 acc3[4];
      #pragma unroll
      for (int j = 0; j < 4; ++j) acc3[j] = vzero;
      #pragma unroll
      for (int ks = 0; ks < 8; ++ks) {
        int k = ks * 32 + quad * 8;
        half8 af = (k < 128) ? *(const half8*)&sh_h16[Rc * LDH + k]
                             : *(const half8*)&sh_agg16[Rc * LDH + k - 128];
        #pragma unroll
        for (int nt = 0; nt < 4; ++nt) {
          half8 bf = *(const half8*)&nw1t[(nc * 64 + nt * 16 + ln) * 256 + k];
          acc3[nt] = __builtin_amdgcn_mfma_f32_16x16x32_f16(af, bf, acc3[nt], 0, 0, 0);
        }
      }
      #pragma unroll
      for (int nt = 0; nt < 4; ++nt) {
        int J = nc * 64 + nt * 16 + ln;
        float b = nb1[J];
        #pragma unroll
        for (int r = 0; r < 4; ++r) {
          int Rr = mt * 16 + quad * 4 + r;
          float v = fmaxf(acc3[nt][r] + b, 0.f);
          C3c[Rr * LDC + nt * 16 + ln] = (_Float16)v;
        }
      }
    }
    __syncthreads();
    #pragma unroll
    for (int ks = 0; ks < 2; ++ks) {
      int k = ks * 32 + quad * 8;
      half8 af[2];
      for (int u = 0; u < nmt; ++u)
        af[u] = *(const half8*)&C3c[(mts[u] * 16 + ln) * LDC + k];
      #pragma unroll
      for (int nt2 = 0; nt2 < 8; ++nt2) {
        half8 bf = *(const half8*)&nw2t[(nt2 * 16 + ln) * 256 + nc * 64 + k];
        for (int u = 0; u < nmt; ++u)
          acc4[u][nt2] = __builtin_amdgcn_mfma_f32_16x16x32_f16(af[u], bf, acc4[u][nt2], 0, 0, 0);
      }
    }
    __syncthreads();
  }

  // ---- final epilogue: residual + LayerNorm + mask ----
  float gam[8], bet[8], nb2v[8];
  #pragma unroll
  for (int nt2 = 0; nt2 < 8; ++nt2) {
    int d = nt2 * 16 + ln;
    gam[nt2] = gamma[d]; bet[nt2] = beta[d]; nb2v[nt2] = nb2[d];
  }
  const size_t obase = (size_t)n0 * 2176;
  for (int u = 0; u < nmt; ++u) {
    int mt = mts[u];
    float xv[8][4];
    #pragma unroll
    for (int nt2 = 0; nt2 < 8; ++nt2) {
      int d = nt2 * 16 + ln;
      #pragma unroll
      for (int r = 0; r < 4; ++r) {
        int R = mt * 16 + quad * 4 + r;
        int Rc = R < 68 ? R : 67;
        float delta = acc4[u][nt2][r] + nb2v[nt2];
        float hh = (float)sh_h16[Rc * LDH + d];
        xv[nt2][r] = hh + delta * sh_hasn[Rc];
      }
    }
    #pragma unroll
    for (int r = 0; r < 4; ++r) {
      float s = 0.f, s2 = 0.f;
      #pragma unroll
      for (int nt2 = 0; nt2 < 8; ++nt2) { float x = xv[nt2][r]; s += x; s2 += x * x; }
      #pragma unroll
      for (int m = 1; m < 16; m <<= 1) {
        s  += __shfl_xor(s, m, 64);
        s2 += __shfl_xor(s2, m, 64);
      }
      float mu   = s * (1.f / 128.f);
      float var  = s2 * (1.f / 128.f) - mu * mu;
      float rstd = rsqrtf(var + 1e-5f);
      int R = mt * 16 + quad * 4 + r;
      if (R < 68) {
        float mk = sh_maskf[R];
        #pragma unroll
        for (int nt2 = 0; nt2 < 8; ++nt2) {
          int d = nt2 * 16 + ln;
          float o = (xv[nt2][r] - mu) * rstd * gam[nt2] + bet[nt2];
          out[obase + (size_t)R * 128 + d] = o * mk;
        }
      }
    }
  }
}

extern "C" void kernel_launch(void* const* d_in, const int* in_sizes, int n_in,
                              void* d_out, int out_size, void* d_ws, size_t ws_size,
                              hipStream_t stream) {
  const float* h     = (const float*)d_in[0];
  const float* xy    = (const float*)d_in[1];
  const int*   jm    = (const int*)d_in[2];
  const int*   ei    = (const int*)d_in[3];
  const float* ew1   = (const float*)d_in[4];
  const float* eb1   = (const float*)d_in[5];
  const float* ew2   = (const float*)d_in[6];
  const float* eb2   = (const float*)d_in[7];
  const float* nw1   = (const float*)d_in[8];
  const float* nb1   = (const float*)d_in[9];
  const float* nw2   = (const float*)d_in[10];
  const float* nb2   = (const float*)d_in[11];
  const float* gamma = (const float*)d_in[12];
  const float* beta  = (const float*)d_in[13];
  _Float16* wz = (_Float16*)d_ws;

  prep_weights<<<768, 256, 0, stream>>>(ew1, ew2, nw1, nw2, wz);
  fused_graph_layer<<<4096, 256, 0, stream>>>(h, xy, jm, ei, ew1, eb1, eb2,
                                              nb1, nb2, gamma, beta, wz,
                                              (float*)d_out);
}

// Round 2
// 2009.915 us; speedup vs baseline: 1.1346x; 1.1346x over previous
//
#include <hip/hip_runtime.h>

typedef _Float16 half8 __attribute__((ext_vector_type(8)));
typedef _Float16 half4v __attribute__((ext_vector_type(4)));
typedef float f32x4 __attribute__((ext_vector_type(4)));

#define LDH 136   // padded fp16 row stride for h16/agg16
#define LDC 72    // padded fp16 row stride for per-wave C scratch

// ---------------- weight prep: fp32 [k][n] -> fp16 [n][k] in d_ws ----------------
// layout (fp16 elements): w1t @0 (256x256), w2t @65536 (128x256),
//                         nw1t @98304 (256x256), nw2t @163840 (128x256)
__global__ void prep_weights(const float* __restrict__ ew1,
                             const float* __restrict__ ew2,
                             const float* __restrict__ nw1,
                             const float* __restrict__ nw2,
                             _Float16* __restrict__ wz) {
  int idx = blockIdx.x * 256 + threadIdx.x;
  if (idx < 65536) {                       // ew1 rows k<256 (rel rows handled in epilogue)
    int k = idx >> 8, n = idx & 255;
    wz[n * 256 + k] = (_Float16)ew1[idx];
  } else if (idx < 98304) {
    int s = idx - 65536;
    int k = s >> 7, n = s & 127;
    wz[65536 + n * 256 + k] = (_Float16)ew2[s];
  } else if (idx < 163840) {
    int s = idx - 98304;
    int k = s >> 8, n = s & 255;
    wz[98304 + n * 256 + k] = (_Float16)nw1[s];
  } else if (idx < 196608) {
    int s = idx - 163840;
    int k = s >> 7, n = s & 127;
    wz[163840 + n * 256 + k] = (_Float16)nw2[s];
  }
}

// ---------------- fused graph layer: 2 batches per block, 4 waves ----------------
// wave w owns edge m-tile w (16 of 64 edge-rows) and node m-tile w (w<3).
// Per-wave C scratch => no barriers inside the GEMM chains.
__global__ __launch_bounds__(256, 4)
void fused_graph_layer(const float* __restrict__ h, const float* __restrict__ xy,
                       const int* __restrict__ jmask, const int* __restrict__ eidx,
                       const float* __restrict__ ew1,   // rel rows 256,257
                       const float* __restrict__ eb1, const float* __restrict__ eb2,
                       const float* __restrict__ nb1, const float* __restrict__ nb2,
                       const float* __restrict__ gamma, const float* __restrict__ beta,
                       const _Float16* __restrict__ wz,
                       float* __restrict__ out) {
  __shared__ _Float16 sh_h16[2 * 17 * LDH];     // 9248 B
  __shared__ _Float16 sh_agg16[2 * 17 * LDH];   // 9248 B
  __shared__ float    sh_B[2 * 17 * 128];       // 17408 B: per-wave C scratch / agg32
  __shared__ float    sh_rel[64 * 2];
  __shared__ float    sh_valid[64];
  __shared__ float    sh_denom[34];
  __shared__ float    sh_hasn[34];
  __shared__ float    sh_maskf[34];
  __shared__ int      sh_edge[64];

  const int tid  = threadIdx.x;
  const int wave = tid >> 6;
  const int lane = tid & 63;
  const int ln   = lane & 15;
  const int quad = lane >> 4;
  const int n0   = blockIdx.x * 2;
  const size_t hbase = (size_t)n0 * (17 * 128);
  const f32x4 vzero = {0.f, 0.f, 0.f, 0.f};

  // ---- stage h -> fp16 LDS; edge list; mask ----
  if (tid < 64) sh_edge[tid] = eidx[tid];
  if (tid < 34) sh_maskf[tid] = (float)jmask[n0 * 17 + tid];
  for (int i = tid; i < 1088; i += 256) {           // 4352 floats as float4
    const float4 hv = ((const float4*)(h + hbase))[i];
    int q = i << 2;
    int gv = q >> 7, d = q & 127;
    half4v hq = { (_Float16)hv.x, (_Float16)hv.y, (_Float16)hv.z, (_Float16)hv.w };
    *(half4v*)&sh_h16[gv * LDH + d] = hq;
  }
  __syncthreads();                                   // barrier 1
  if (tid < 64) {                                    // rel + edge_valid per (g,e)
    int g = tid >> 5, e = tid & 31;
    int dv = sh_edge[2 * e], sv = sh_edge[2 * e + 1];
    const float* xyb = xy + (size_t)(n0 + g) * 34;
    sh_rel[2 * tid]     = xyb[2 * sv]     - xyb[2 * dv];
    sh_rel[2 * tid + 1] = xyb[2 * sv + 1] - xyb[2 * dv + 1];
    sh_valid[tid] = sh_maskf[g * 17 + dv] * sh_maskf[g * 17 + sv];
  }
  __syncthreads();                                   // barrier 2
  if (tid < 34) {                                    // denom per (g,v); visible by barrier 4/5
    int g = tid < 17 ? 0 : 1, v = tid - g * 17;
    float den = 0.f;
    for (int e = 0; e < 32; ++e)
      if (sh_edge[2 * e] == v) den += sh_valid[g * 32 + e];
    sh_denom[tid] = den;
    sh_hasn[tid]  = den > 0.f ? 1.f : 0.f;
  }

  const _Float16* w1t  = wz;
  const _Float16* w2t  = wz + 65536;
  const _Float16* nw1t = wz + 98304;
  const _Float16* nw2t = wz + 163840;
  const float* w1r0 = ew1 + 256 * 256;
  const float* w1r1 = ew1 + 257 * 256;
  _Float16* myC = (_Float16*)sh_B + wave * (16 * LDC);   // per-wave scratch

  // ================= EDGE PHASE: rows R = wave*16 + ln (g = R>>5, e = R&31) ======
  const int Re   = wave * 16 + ln;
  const int ge   = Re >> 5, ee = Re & 31;
  const int baseT = (ge * 17 + sh_edge[2 * ee]) * LDH;
  const int baseS = (ge * 17 + sh_edge[2 * ee + 1]) * LDH;

  f32x4 acc2[8];
  #pragma unroll
  for (int j = 0; j < 8; ++j) acc2[j] = vzero;

  for (int nc = 0; nc < 4; ++nc) {
    f32x4 acc1[4];
    #pragma unroll
    for (int j = 0; j < 4; ++j) acc1[j] = vzero;
    #pragma unroll
    for (int ks = 0; ks < 8; ++ks) {
      int k = ks * 32 + quad * 8;
      half8 af = (ks < 4) ? *(const half8*)&sh_h16[baseT + k]
                          : *(const half8*)&sh_h16[baseS + k - 128];
      #pragma unroll
      for (int nt = 0; nt < 4; ++nt) {
        half8 bf = *(const half8*)&w1t[(nc * 64 + nt * 16 + ln) * 256 + k];
        acc1[nt] = __builtin_amdgcn_mfma_f32_16x16x32_f16(af, bf, acc1[nt], 0, 0, 0);
      }
    }
    // epilogue: + eb1 + rel·W1rel, relu, fp16 -> per-wave scratch
    #pragma unroll
    for (int nt = 0; nt < 4; ++nt) {
      int J = nc * 64 + nt * 16 + ln;
      float b = eb1[J], r0 = w1r0[J], r1 = w1r1[J];
      #pragma unroll
      for (int r = 0; r < 4; ++r) {
        int R = wave * 16 + quad * 4 + r;
        float val = acc1[nt][r] + b + sh_rel[2 * R] * r0 + sh_rel[2 * R + 1] * r1;
        C_STORE: ;
        myC[(quad * 4 + r) * LDC + nt * 16 + ln] = (_Float16)fmaxf(val, 0.f);
      }
    }
    // GEMM2 partial-K accumulate (reads own wave's scratch; lgkmcnt handles dep)
    #pragma unroll
    for (int ks = 0; ks < 2; ++ks) {
      int k = ks * 32 + quad * 8;
      half8 af2 = *(const half8*)&myC[ln * LDC + k];
      #pragma unroll
      for (int nt2 = 0; nt2 < 8; ++nt2) {
        half8 bf2 = *(const half8*)&w2t[(nt2 * 16 + ln) * 256 + nc * 64 + k];
        acc2[nt2] = __builtin_amdgcn_mfma_f32_16x16x32_f16(af2, bf2, acc2[nt2], 0, 0, 0);
      }
    }
  }

  // ---- aggregate messages: zero agg32, LDS atomics, normalize -> agg16 ----
  __syncthreads();                                   // barrier 3: C scratch dead
  for (int i = tid; i < 4352; i += 256) sh_B[i] = 0.f;
  __syncthreads();                                   // barrier 4
  #pragma unroll
  for (int nt2 = 0; nt2 < 8; ++nt2) {
    int d = nt2 * 16 + ln;
    float b2 = eb2[d];
    #pragma unroll
    for (int r = 0; r < 4; ++r) {
      int R = wave * 16 + quad * 4 + r;
      int g = R >> 5, e = R & 31;
      float msg = (acc2[nt2][r] + b2) * sh_valid[R];
      atomicAdd(&sh_B[(g * 17 + sh_edge[2 * e]) * 128 + d], msg);
    }
  }
  __syncthreads();                                   // barrier 5
  for (int i = tid; i < 4352; i += 256) {
    int gv = i >> 7, d = i & 127;
    float den = fmaxf(sh_denom[gv], 1.f);
    sh_agg16[gv * LDH + d] = (_Float16)(sh_B[i] / den);
  }
  __syncthreads();                                   // barrier 6 (last)

  // ================= NODE PHASE: rows R = g*17+v in [0,34); waves 0..2 ==========
  if (wave < 3) {
    const int Rn  = wave * 16 + ln;
    const int Rc  = Rn < 34 ? Rn : 33;

    f32x4 acc4[8];
    #pragma unroll
    for (int j = 0; j < 8; ++j) acc4[j] = vzero;

    for (int nc = 0; nc < 4; ++nc) {
      f32x4 acc3[4];
      #pragma unroll
      for (int j = 0; j < 4; ++j) acc3[j] = vzero;
      #pragma unroll
      for (int ks = 0; ks < 8; ++ks) {
        int k = ks * 32 + quad * 8;
        half8 af = (ks < 4) ? *(const half8*)&sh_h16[Rc * LDH + k]
                            : *(const half8*)&sh_agg16[Rc * LDH + k - 128];
        #pragma unroll
        for (int nt = 0; nt < 4; ++nt) {
          half8 bf = *(const half8*)&nw1t[(nc * 64 + nt * 16 + ln) * 256 + k];
          acc3[nt] = __builtin_amdgcn_mfma_f32_16x16x32_f16(af, bf, acc3[nt], 0, 0, 0);
        }
      }
      #pragma unroll
      for (int nt = 0; nt < 4; ++nt) {
        int J = nc * 64 + nt * 16 + ln;
        float b = nb1[J];
        #pragma unroll
        for (int r = 0; r < 4; ++r)
          myC[(quad * 4 + r) * LDC + nt * 16 + ln] =
              (_Float16)fmaxf(acc3[nt][r] + b, 0.f);
      }
      #pragma unroll
      for (int ks = 0; ks < 2; ++ks) {
        int k = ks * 32 + quad * 8;
        half8 af2 = *(const half8*)&myC[ln * LDC + k];
        #pragma unroll
        for (int nt2 = 0; nt2 < 8; ++nt2) {
          half8 bf2 = *(const half8*)&nw2t[(nt2 * 16 + ln) * 256 + nc * 64 + k];
          acc4[nt2] = __builtin_amdgcn_mfma_f32_16x16x32_f16(af2, bf2, acc4[nt2], 0, 0, 0);
        }
      }
    }

    // ---- final epilogue: residual + LayerNorm + mask ----
    float gam[8], bet[8], nb2v[8];
    #pragma unroll
    for (int nt2 = 0; nt2 < 8; ++nt2) {
      int d = nt2 * 16 + ln;
      gam[nt2] = gamma[d]; bet[nt2] = beta[d]; nb2v[nt2] = nb2[d];
    }
    const size_t obase = (size_t)n0 * 2176;
    float xv[8][4];
    #pragma unroll
    for (int nt2 = 0; nt2 < 8; ++nt2) {
      int d = nt2 * 16 + ln;
      #pragma unroll
      for (int r = 0; r < 4; ++r) {
        int R = wave * 16 + quad * 4 + r;
        int Rc2 = R < 34 ? R : 33;
        float delta = acc4[nt2][r] + nb2v[nt2];
        float hh = (float)sh_h16[Rc2 * LDH + d];
        xv[nt2][r] = hh + delta * sh_hasn[Rc2];
      }
    }
    #pragma unroll
    for (int r = 0; r < 4; ++r) {
      float s = 0.f, s2 = 0.f;
      #pragma unroll
      for (int nt2 = 0; nt2 < 8; ++nt2) { float x = xv[nt2][r]; s += x; s2 += x * x; }
      #pragma unroll
      for (int m = 1; m < 16; m <<= 1) {
        s  += __shfl_xor(s, m, 64);
        s2 += __shfl_xor(s2, m, 64);
      }
      float mu   = s * (1.f / 128.f);
      float var  = s2 * (1.f / 128.f) - mu * mu;
      float rstd = rsqrtf(var + 1e-5f);
      int R = wave * 16 + quad * 4 + r;
      if (R < 34) {
        float mk = sh_maskf[R];
        #pragma unroll
        for (int nt2 = 0; nt2 < 8; ++nt2) {
          int d = nt2 * 16 + ln;
          float o = (xv[nt2][r] - mu) * rstd * gam[nt2] + bet[nt2];
          out[obase + (size_t)R * 128 + d] = o * mk;
        }
      }
    }
  }
}

extern "C" void kernel_launch(void* const* d_in, const int* in_sizes, int n_in,
                              void* d_out, int out_size, void* d_ws, size_t ws_size,
                              hipStream_t stream) {
  const float* h     = (const float*)d_in[0];
  const float* xy    = (const float*)d_in[1];
  const int*   jm    = (const int*)d_in[2];
  const int*   ei    = (const int*)d_in[3];
  const float* ew1   = (const float*)d_in[4];
  const float* eb1   = (const float*)d_in[5];
  const float* ew2   = (const float*)d_in[6];
  const float* eb2   = (const float*)d_in[7];
  const float* nw1   = (const float*)d_in[8];
  const float* nb1   = (const float*)d_in[9];
  const float* nw2   = (const float*)d_in[10];
  const float* nb2   = (const float*)d_in[11];
  const float* gamma = (const float*)d_in[12];
  const float* beta  = (const float*)d_in[13];
  _Float16* wz = (_Float16*)d_ws;

  prep_weights<<<768, 256, 0, stream>>>(ew1, ew2, nw1, nw2, wz);
  fused_graph_layer<<<8192, 256, 0, stream>>>(h, xy, jm, ei, ew1, eb1, eb2,
                                              nb1, nb2, gamma, beta, wz,
                                              (float*)d_out);
}

// Round 3
// 1237.201 us; speedup vs baseline: 1.8433x; 1.6246x over previous
//
#include <hip/hip_runtime.h>

typedef _Float16 half8 __attribute__((ext_vector_type(8)));
typedef _Float16 half4v __attribute__((ext_vector_type(4)));
typedef float f32x4 __attribute__((ext_vector_type(4)));

#define LDH  136   // h16/agg16 row stride (halves), 272 B (16B-aligned, 2-way banks)
#define LDW1 264   // w1/nw1 chunk row stride (halves), 528 B
#define LDW2 40    // w2/nw2 chunk row stride (halves), 80 B
#define LDCX 40    // per-wave C scratch row stride (halves)
#define LDA  132   // agg32 / out-stage row stride (floats)

// ---------------- weight prep: fp32 [k][n] -> fp16 [n][k] in d_ws ----------------
__global__ void prep_weights(const float* __restrict__ ew1,
                             const float* __restrict__ ew2,
                             const float* __restrict__ nw1,
                             const float* __restrict__ nw2,
                             _Float16* __restrict__ wz) {
  int idx = blockIdx.x * 256 + threadIdx.x;
  if (idx < 65536) {                       // ew1 rows k<256 (rel rows in epilogue)
    int k = idx >> 8, n = idx & 255;
    wz[n * 256 + k] = (_Float16)ew1[idx];
  } else if (idx < 98304) {
    int s = idx - 65536;
    int k = s >> 7, n = s & 127;
    wz[65536 + n * 256 + k] = (_Float16)ew2[s];
  } else if (idx < 163840) {
    int s = idx - 98304;
    int k = s >> 8, n = s & 255;
    wz[98304 + n * 256 + k] = (_Float16)nw1[s];
  } else if (idx < 196608) {
    int s = idx - 163840;
    int k = s >> 7, n = s & 127;
    wz[163840 + n * 256 + k] = (_Float16)nw2[s];
  }
}

// ---------------- fused layer: 4 batches/block, 4 waves, LDS-staged weights ------
__global__ __launch_bounds__(256, 2)
void fused_graph_layer(const float* __restrict__ h, const float* __restrict__ xy,
                       const int* __restrict__ jmask, const int* __restrict__ eidx,
                       const float* __restrict__ ew1,   // rel rows 256,257
                       const float* __restrict__ eb1, const float* __restrict__ eb2,
                       const float* __restrict__ nb1, const float* __restrict__ nb2,
                       const float* __restrict__ gamma, const float* __restrict__ beta,
                       const _Float16* __restrict__ wz,
                       float* __restrict__ out) {
  __shared__ _Float16 sh_h16[68 * LDH];        // 18496 B
  __shared__ _Float16 sh_agg16[68 * LDH];      // 18496 B
  __shared__ __align__(16) char uni[37376];    // W chunks + C scratch | agg32 | out-stage
  __shared__ float sh_rel[128 * 2];
  __shared__ float sh_valid[128];
  __shared__ float sh_denom[68];
  __shared__ float sh_hasn[68];
  __shared__ float sh_maskf[68];
  __shared__ int   sh_edge[64];

  const int tid  = threadIdx.x;
  const int wave = tid >> 6;
  const int lane = tid & 63;
  const int ln   = lane & 15;
  const int quad = lane >> 4;
  const int n0   = blockIdx.x * 4;
  const size_t hbase = (size_t)n0 * 2176;
  const f32x4 vzero = {0.f, 0.f, 0.f, 0.f};

  _Float16* w1b = (_Float16*)uni;                       // 32 x LDW1   (16896 B)
  _Float16* w2b = (_Float16*)(uni + 16896);             // 128 x LDW2  (10240 B)
  _Float16* myC = (_Float16*)(uni + 27136) + wave * 1280; // 32 x LDCX per wave

  // ---- stage h -> fp16 LDS; edge list; mask ----
  if (tid < 64) sh_edge[tid] = eidx[tid];
  if (tid < 68) sh_maskf[tid] = (float)jmask[n0 * 17 + tid];
  for (int i = tid; i < 2176; i += 256) {
    const float4 hv = ((const float4*)(h + hbase))[i];
    int q = i << 2;
    int gv = q >> 7, d = q & 127;
    half4v hq = { (_Float16)hv.x, (_Float16)hv.y, (_Float16)hv.z, (_Float16)hv.w };
    *(half4v*)&sh_h16[gv * LDH + d] = hq;
  }
  __syncthreads();                                      // S1
  if (tid < 128) {                                      // rel + edge_valid per (g,e)
    int g = tid >> 5, e = tid & 31;
    int dv = sh_edge[2 * e], sv = sh_edge[2 * e + 1];
    const float* xyb = xy + (size_t)(n0 + g) * 34;
    sh_rel[2 * tid]     = xyb[2 * sv]     - xyb[2 * dv];
    sh_rel[2 * tid + 1] = xyb[2 * sv + 1] - xyb[2 * dv + 1];
    sh_valid[tid] = sh_maskf[g * 17 + dv] * sh_maskf[g * 17 + sv];
  }
  __syncthreads();                                      // S2
  if (tid < 68) {                                       // denom per (g,v)
    int g = tid / 17, v = tid - g * 17;
    float den = 0.f;
    for (int e = 0; e < 32; ++e)
      if (sh_edge[2 * e] == v) den += sh_valid[g * 32 + e];
    sh_denom[tid] = den;
    sh_hasn[tid]  = den > 0.f ? 1.f : 0.f;
  }

  // ---- per-lane hoists (valid after S2) ----
  int baseT[2], baseS[2];
  float rel0[2][4], rel1[2][4], vld[2][4];
  int dstOff[2][4];
  #pragma unroll
  for (int mi = 0; mi < 2; ++mi) {
    int eL = mi * 16 + ln;
    baseT[mi] = (wave * 17 + sh_edge[2 * eL]) * LDH;
    baseS[mi] = (wave * 17 + sh_edge[2 * eL + 1]) * LDH;
    #pragma unroll
    for (int r = 0; r < 4; ++r) {
      int e = mi * 16 + quad * 4 + r;
      int R = wave * 32 + e;
      rel0[mi][r] = sh_rel[2 * R];
      rel1[mi][r] = sh_rel[2 * R + 1];
      vld[mi][r]  = sh_valid[R];
      dstOff[mi][r] = (wave * 17 + sh_edge[2 * e]) * LDA;
    }
  }

  const _Float16* w1t  = wz;
  const _Float16* w2t  = wz + 65536;
  const _Float16* nw1t = wz + 98304;
  const _Float16* nw2t = wz + 163840;
  const float* w1r0 = ew1 + 256 * 256;
  const float* w1r1 = ew1 + 257 * 256;

  // ================= EDGE PHASE =================
  f32x4 acc2[2][8];
  #pragma unroll
  for (int i = 0; i < 2; ++i)
    #pragma unroll
    for (int j = 0; j < 8; ++j) acc2[i][j] = vzero;

  for (int nc = 0; nc < 8; ++nc) {
    __syncthreads();                                    // old chunk fully consumed
    for (int u = tid; u < 1024; u += 256) {             // w1 chunk: 32 n-rows x 256 k
      int row = u >> 5, c8 = u & 31;
      *(half8*)&w1b[row * LDW1 + c8 * 8] =
          *(const half8*)&w1t[(nc * 32 + row) * 256 + c8 * 8];
    }
    for (int u = tid; u < 512; u += 256) {              // w2 chunk: 128 n-rows x 32 k
      int row = u >> 2, c8 = u & 3;
      *(half8*)&w2b[row * LDW2 + c8 * 8] =
          *(const half8*)&w2t[row * 256 + nc * 32 + c8 * 8];
    }
    __syncthreads();

    f32x4 acc1[2][2];
    #pragma unroll
    for (int i = 0; i < 2; ++i)
      #pragma unroll
      for (int j = 0; j < 2; ++j) acc1[i][j] = vzero;
    #pragma unroll
    for (int ks = 0; ks < 8; ++ks) {
      int k = ks * 32 + quad * 8;
      half8 af[2];
      #pragma unroll
      for (int mi = 0; mi < 2; ++mi)
        af[mi] = (ks < 4) ? *(const half8*)&sh_h16[baseT[mi] + k]
                          : *(const half8*)&sh_h16[baseS[mi] + k - 128];
      half8 bf[2];
      #pragma unroll
      for (int nt = 0; nt < 2; ++nt)
        bf[nt] = *(const half8*)&w1b[(nt * 16 + ln) * LDW1 + k];
      #pragma unroll
      for (int mi = 0; mi < 2; ++mi)
        #pragma unroll
        for (int nt = 0; nt < 2; ++nt)
          acc1[mi][nt] = __builtin_amdgcn_mfma_f32_16x16x32_f16(af[mi], bf[nt], acc1[mi][nt], 0, 0, 0);
    }
    #pragma unroll
    for (int nt = 0; nt < 2; ++nt) {
      int J = nc * 32 + nt * 16 + ln;
      float b = eb1[J], r0 = w1r0[J], r1 = w1r1[J];
      #pragma unroll
      for (int mi = 0; mi < 2; ++mi)
        #pragma unroll
        for (int r = 0; r < 4; ++r) {
          float val = acc1[mi][nt][r] + b + rel0[mi][r] * r0 + rel1[mi][r] * r1;
          myC[(mi * 16 + quad * 4 + r) * LDCX + nt * 16 + ln] = (_Float16)fmaxf(val, 0.f);
        }
    }
    // GEMM2 partial-K (k_local = quad*8 spans the 32-chunk)
    {
      int k2 = quad * 8;
      half8 a2[2];
      #pragma unroll
      for (int mi = 0; mi < 2; ++mi)
        a2[mi] = *(const half8*)&myC[(mi * 16 + ln) * LDCX + k2];
      #pragma unroll
      for (int nt2 = 0; nt2 < 8; ++nt2) {
        half8 b2 = *(const half8*)&w2b[(nt2 * 16 + ln) * LDW2 + k2];
        #pragma unroll
        for (int mi = 0; mi < 2; ++mi)
          acc2[mi][nt2] = __builtin_amdgcn_mfma_f32_16x16x32_f16(a2[mi], b2, acc2[mi][nt2], 0, 0, 0);
      }
    }
  }

  // ---- aggregate: zero agg32, LDS atomics, normalize -> agg16 ----
  __syncthreads();
  float* agg32 = (float*)uni;
  for (int i = tid; i < 68 * LDA; i += 256) agg32[i] = 0.f;
  __syncthreads();
  #pragma unroll
  for (int nt2 = 0; nt2 < 8; ++nt2) {
    int d = nt2 * 16 + ln;
    float b2 = eb2[d];
    #pragma unroll
    for (int mi = 0; mi < 2; ++mi)
      #pragma unroll
      for (int r = 0; r < 4; ++r) {
        float msg = (acc2[mi][nt2][r] + b2) * vld[mi][r];
        atomicAdd(&agg32[dstOff[mi][r] + d], msg);
      }
  }
  __syncthreads();
  for (int i = tid; i < 8704; i += 256) {
    int gv = i >> 7, d = i & 127;
    float den = fmaxf(sh_denom[gv], 1.f);
    sh_agg16[gv * LDH + d] = (_Float16)(agg32[gv * LDA + d] / den);
  }

  // ================= NODE PHASE: 68 rows = 5 m-tiles =================
  const int nTiles = (wave == 0) ? 2 : 1;
  int tiles[2]; tiles[0] = wave; tiles[1] = 4;

  f32x4 acc4[2][8];
  #pragma unroll
  for (int i = 0; i < 2; ++i)
    #pragma unroll
    for (int j = 0; j < 8; ++j) acc4[i][j] = vzero;

  for (int nc = 0; nc < 8; ++nc) {
    __syncthreads();
    for (int u = tid; u < 1024; u += 256) {
      int row = u >> 5, c8 = u & 31;
      *(half8*)&w1b[row * LDW1 + c8 * 8] =
          *(const half8*)&nw1t[(nc * 32 + row) * 256 + c8 * 8];
    }
    for (int u = tid; u < 512; u += 256) {
      int row = u >> 2, c8 = u & 3;
      *(half8*)&w2b[row * LDW2 + c8 * 8] =
          *(const half8*)&nw2t[row * 256 + nc * 32 + c8 * 8];
    }
    __syncthreads();

    for (int t = 0; t < nTiles; ++t) {
      int mt = tiles[t];
      int Rr = mt * 16 + ln;
      int Rc = Rr < 68 ? Rr : 67;
      f32x4 acc3[2];
      #pragma unroll
      for (int j = 0; j < 2; ++j) acc3[j] = vzero;
      #pragma unroll
      for (int ks = 0; ks < 8; ++ks) {
        int k = ks * 32 + quad * 8;
        half8 af = (ks < 4) ? *(const half8*)&sh_h16[Rc * LDH + k]
                            : *(const half8*)&sh_agg16[Rc * LDH + k - 128];
        #pragma unroll
        for (int nt = 0; nt < 2; ++nt) {
          half8 bf = *(const half8*)&w1b[(nt * 16 + ln) * LDW1 + k];
          acc3[nt] = __builtin_amdgcn_mfma_f32_16x16x32_f16(af, bf, acc3[nt], 0, 0, 0);
        }
      }
      #pragma unroll
      for (int nt = 0; nt < 2; ++nt) {
        int J = nc * 32 + nt * 16 + ln;
        float b = nb1[J];
        #pragma unroll
        for (int r = 0; r < 4; ++r)
          myC[(t * 16 + quad * 4 + r) * LDCX + nt * 16 + ln] =
              (_Float16)fmaxf(acc3[nt][r] + b, 0.f);
      }
      {
        int k2 = quad * 8;
        half8 a2 = *(const half8*)&myC[(t * 16 + ln) * LDCX + k2];
        #pragma unroll
        for (int nt2 = 0; nt2 < 8; ++nt2) {
          half8 b2 = *(const half8*)&w2b[(nt2 * 16 + ln) * LDW2 + k2];
          acc4[t][nt2] = __builtin_amdgcn_mfma_f32_16x16x32_f16(a2, b2, acc4[t][nt2], 0, 0, 0);
        }
      }
    }
  }

  // ---- final epilogue: residual + LayerNorm + mask -> LDS stage -> coalesced out
  __syncthreads();                                      // W/C dead; uni becomes out-stage
  float* ost = (float*)uni;
  float gam[8], bet[8], nb2v[8];
  #pragma unroll
  for (int nt2 = 0; nt2 < 8; ++nt2) {
    int d = nt2 * 16 + ln;
    gam[nt2] = gamma[d]; bet[nt2] = beta[d]; nb2v[nt2] = nb2[d];
  }
  for (int t = 0; t < nTiles; ++t) {
    int mt = tiles[t];
    float xv[8][4];
    #pragma unroll
    for (int nt2 = 0; nt2 < 8; ++nt2) {
      int d = nt2 * 16 + ln;
      #pragma unroll
      for (int r = 0; r < 4; ++r) {
        int R = mt * 16 + quad * 4 + r;
        int Rc2 = R < 68 ? R : 67;
        float delta = acc4[t][nt2][r] + nb2v[nt2];
        float hh = (float)sh_h16[Rc2 * LDH + d];
        xv[nt2][r] = hh + delta * sh_hasn[Rc2];
      }
    }
    #pragma unroll
    for (int r = 0; r < 4; ++r) {
      float s = 0.f, s2 = 0.f;
      #pragma unroll
      for (int nt2 = 0; nt2 < 8; ++nt2) { float x = xv[nt2][r]; s += x; s2 += x * x; }
      #pragma unroll
      for (int m = 1; m < 16; m <<= 1) {
        s  += __shfl_xor(s, m, 64);
        s2 += __shfl_xor(s2, m, 64);
      }
      float mu   = s * (1.f / 128.f);
      float var  = s2 * (1.f / 128.f) - mu * mu;
      float rstd = rsqrtf(var + 1e-5f);
      int R = mt * 16 + quad * 4 + r;
      if (R < 68) {
        float mk = sh_maskf[R];
        #pragma unroll
        for (int nt2 = 0; nt2 < 8; ++nt2) {
          int d = nt2 * 16 + ln;
          ost[R * LDA + d] = ((xv[nt2][r] - mu) * rstd * gam[nt2] + bet[nt2]) * mk;
        }
      }
    }
  }
  __syncthreads();
  for (int i = tid; i < 8704; i += 256)
    out[hbase + i] = ost[(i >> 7) * LDA + (i & 127)];
}

extern "C" void kernel_launch(void* const* d_in, const int* in_sizes, int n_in,
                              void* d_out, int out_size, void* d_ws, size_t ws_size,
                              hipStream_t stream) {
  const float* h     = (const float*)d_in[0];
  const float* xy    = (const float*)d_in[1];
  const int*   jm    = (const int*)d_in[2];
  const int*   ei    = (const int*)d_in[3];
  const float* ew1   = (const float*)d_in[4];
  const float* eb1   = (const float*)d_in[5];
  const float* ew2   = (const float*)d_in[6];
  const float* eb2   = (const float*)d_in[7];
  const float* nw1   = (const float*)d_in[8];
  const float* nb1   = (const float*)d_in[9];
  const float* nw2   = (const float*)d_in[10];
  const float* nb2   = (const float*)d_in[11];
  const float* gamma = (const float*)d_in[12];
  const float* beta  = (const float*)d_in[13];
  _Float16* wz = (_Float16*)d_ws;

  prep_weights<<<768, 256, 0, stream>>>(ew1, ew2, nw1, nw2, wz);
  fused_graph_layer<<<4096, 256, 0, stream>>>(h, xy, jm, ei, ew1, eb1, eb2,
                                              nb1, nb2, gamma, beta, wz,
                                              (float*)d_out);
}

// Round 4
// 891.012 us; speedup vs baseline: 2.5595x; 1.3885x over previous
//
#include <hip/hip_runtime.h>

typedef _Float16 half8 __attribute__((ext_vector_type(8)));
typedef _Float16 half4v __attribute__((ext_vector_type(4)));
typedef float f32x4 __attribute__((ext_vector_type(4)));
typedef unsigned int u32;

#define LDH 136   // fp16 row stride for h16/agg16 (+8 halves pad -> 4-word bank rotate)

__device__ __forceinline__ void async16(void* lds, const void* g) {
  __builtin_amdgcn_global_load_lds(
      (const __attribute__((address_space(1))) u32*)g,
      (__attribute__((address_space(3))) u32*)lds, 16, 0, 0);
}

// --------- weight prep: fp32 [k][n] -> fp16 MFMA-fragment-ordered images -------
// w1img @0      (65536 h): 16 half-stages x 8 groups x 64 lanes x 8 halves
// w2img @65536  (32768 h): 8 nc-chunks x 8 ntiles x 64 lanes x 8
// nw1img @98304, nw2img @163840 : same layouts
__global__ void prep_weights(const float* __restrict__ ew1,
                             const float* __restrict__ ew2,
                             const float* __restrict__ nw1,
                             const float* __restrict__ nw2,
                             _Float16* __restrict__ wz) {
  int o = blockIdx.x * 256 + threadIdx.x;
  if (o < 65536) {
    int s = o >> 12, r = o & 4095;
    int gs = r >> 9, lane = (r >> 3) & 63, j = r & 7;
    int k = ((s & 1) * 4 + (gs >> 1)) * 32 + (lane >> 4) * 8 + j;
    int n = (s >> 1) * 32 + (gs & 1) * 16 + (lane & 15);
    wz[o] = (_Float16)ew1[k * 256 + n];
  } else if (o < 98304) {
    int o2 = o - 65536;
    int nc = o2 >> 12, r = o2 & 4095;
    int nt2 = r >> 9, lane = (r >> 3) & 63, j = r & 7;
    int k = nc * 32 + (lane >> 4) * 8 + j;
    int n = nt2 * 16 + (lane & 15);
    wz[o] = (_Float16)ew2[k * 128 + n];
  } else if (o < 163840) {
    int o2 = o - 98304;
    int s = o2 >> 12, r = o2 & 4095;
    int gs = r >> 9, lane = (r >> 3) & 63, j = r & 7;
    int k = ((s & 1) * 4 + (gs >> 1)) * 32 + (lane >> 4) * 8 + j;
    int n = (s >> 1) * 32 + (gs & 1) * 16 + (lane & 15);
    wz[o] = (_Float16)nw1[k * 256 + n];
  } else if (o < 196608) {
    int o2 = o - 163840;
    int nc = o2 >> 12, r = o2 & 4095;
    int nt2 = r >> 9, lane = (r >> 3) & 63, j = r & 7;
    int k = nc * 32 + (lane >> 4) * 8 + j;
    int n = nt2 * 16 + (lane & 15);
    wz[o] = (_Float16)nw2[k * 128 + n];
  }
}

// --------- fused layer: 4 batches/block, 4 waves, async dbuf weight staging -----
__global__ __launch_bounds__(256, 2)
void fused_graph_layer(const float* __restrict__ h, const float* __restrict__ xy,
                       const int* __restrict__ jmask, const int* __restrict__ eidx,
                       const float* __restrict__ ew1,   // rel rows 256,257
                       const float* __restrict__ eb1, const float* __restrict__ eb2,
                       const float* __restrict__ nb1, const float* __restrict__ nb2,
                       const float* __restrict__ gamma, const float* __restrict__ beta,
                       const _Float16* __restrict__ wz,
                       float* __restrict__ out) {
  __shared__ _Float16 sh_h16[68 * LDH];                       // 18496 B
  __shared__ _Float16 sh_agg16[68 * LDH];                     // 18496 B
  __shared__ char uni[35904] __attribute__((aligned(16)));    // p0|p1|myC / agg32 / ost
  __shared__ float sh_rel[256];
  __shared__ float sh_valid[128];
  __shared__ float sh_denom[68], sh_hasn[68], sh_maskf[68];
  __shared__ int   sh_edge[64];

  const int tid  = threadIdx.x;
  const int wave = tid >> 6;
  const int lane = tid & 63;
  const int ln   = lane & 15;
  const int quad = lane >> 4;
  const int n0   = blockIdx.x * 4;
  const size_t hbase = (size_t)n0 * 2176;
  const f32x4 vzero = {0.f, 0.f, 0.f, 0.f};

  _Float16* p0  = (_Float16*)uni;                 // 4096 h (8 KB)
  _Float16* p1  = (_Float16*)(uni + 8192);        // 4096 h
  _Float16* myC = (_Float16*)(uni + 16384) + wave * 1280;  // 32 x 40 h per wave

  const _Float16* w1img  = wz;
  const _Float16* w2img  = wz + 65536;
  const _Float16* nw1img = wz + 98304;
  const _Float16* nw2img = wz + 163840;
  const float* w1r0 = ew1 + 256 * 256;
  const float* w1r1 = ew1 + 257 * 256;

  // issue edge stage 0 ASAP (lands during h staging)
  {
    const _Float16* src = w1img + (2 * wave) * 512 + lane * 8;
    async16(p0 + (2 * wave) * 512, src);
    async16(p0 + (2 * wave + 1) * 512, src + 512);
  }

  // ---- stage h -> fp16 LDS; edges; mask ----
  if (tid < 64) sh_edge[tid] = eidx[tid];
  if (tid < 68) sh_maskf[tid] = (float)jmask[n0 * 17 + tid];
  for (int i = tid; i < 2176; i += 256) {
    const float4 hv = ((const float4*)(h + hbase))[i];
    int q = i << 2;
    int gv = q >> 7, d = q & 127;
    half4v hq = { (_Float16)hv.x, (_Float16)hv.y, (_Float16)hv.z, (_Float16)hv.w };
    *(half4v*)&sh_h16[gv * LDH + d] = hq;
  }
  __syncthreads();                                   // S1
  if (tid < 128) {
    int g = tid >> 5, e = tid & 31;
    int dv = sh_edge[2 * e], sv = sh_edge[2 * e + 1];
    const float* xyb = xy + (size_t)(n0 + g) * 34;
    sh_rel[2 * tid]     = xyb[2 * sv]     - xyb[2 * dv];
    sh_rel[2 * tid + 1] = xyb[2 * sv + 1] - xyb[2 * dv + 1];
    sh_valid[tid] = sh_maskf[g * 17 + dv] * sh_maskf[g * 17 + sv];
  }
  __syncthreads();                                   // S2
  if (tid < 68) {
    int g = tid / 17, v = tid - g * 17;
    float den = 0.f;
    for (int e = 0; e < 32; ++e)
      if (sh_edge[2 * e] == v) den += sh_valid[g * 32 + e];
    sh_denom[tid] = den;
    sh_hasn[tid]  = den > 0.f ? 1.f : 0.f;
  }

  // ---- preload edge A fragments into registers (read h16 once) ----
  int baseT[2], baseS[2];
  #pragma unroll
  for (int mi = 0; mi < 2; ++mi) {
    int eL = mi * 16 + ln;
    baseT[mi] = (wave * 17 + sh_edge[2 * eL]) * LDH;
    baseS[mi] = (wave * 17 + sh_edge[2 * eL + 1]) * LDH;
  }
  half8 af[2][8];
  #pragma unroll
  for (int mi = 0; mi < 2; ++mi)
    #pragma unroll
    for (int ks = 0; ks < 8; ++ks)
      af[mi][ks] = (ks < 4)
          ? *(const half8*)&sh_h16[baseT[mi] + ks * 32 + quad * 8]
          : *(const half8*)&sh_h16[baseS[mi] + (ks - 4) * 32 + quad * 8];

  // ================= EDGE PHASE =================
  f32x4 acc2[2][8];
  #pragma unroll
  for (int i = 0; i < 2; ++i)
    #pragma unroll
    for (int j = 0; j < 8; ++j) acc2[i][j] = vzero;

  for (int nc = 0; nc < 8; ++nc) {
    __syncthreads();                                 // even stage 2nc ready in p0
    {
      const _Float16* src = w1img + (size_t)(2 * nc + 1) * 4096 + (2 * wave) * 512 + lane * 8;
      async16(p1 + (2 * wave) * 512, src);
      async16(p1 + (2 * wave + 1) * 512, src + 512);
    }
    half8 b2f[8];
    #pragma unroll
    for (int t = 0; t < 8; ++t)
      b2f[t] = *(const half8*)(w2img + nc * 4096 + t * 512 + lane * 8);
    float ebv[2], r0v[2], r1v[2];
    #pragma unroll
    for (int nt = 0; nt < 2; ++nt) {
      int J = nc * 32 + nt * 16 + ln;
      ebv[nt] = eb1[J]; r0v[nt] = w1r0[J]; r1v[nt] = w1r1[J];
    }
    f32x4 acc1[2][2];
    #pragma unroll
    for (int i = 0; i < 2; ++i) { acc1[i][0] = vzero; acc1[i][1] = vzero; }

    #pragma unroll
    for (int ksl = 0; ksl < 4; ++ksl) {
      half8 bf0 = *(const half8*)&p0[(ksl * 2 + 0) * 512 + lane * 8];
      half8 bf1 = *(const half8*)&p0[(ksl * 2 + 1) * 512 + lane * 8];
      #pragma unroll
      for (int mi = 0; mi < 2; ++mi) {
        acc1[mi][0] = __builtin_amdgcn_mfma_f32_16x16x32_f16(af[mi][ksl], bf0, acc1[mi][0], 0, 0, 0);
        acc1[mi][1] = __builtin_amdgcn_mfma_f32_16x16x32_f16(af[mi][ksl], bf1, acc1[mi][1], 0, 0, 0);
      }
    }
    __syncthreads();                                 // odd stage 2nc+1 ready in p1
    if (nc < 7) {
      const _Float16* src = w1img + (size_t)(2 * nc + 2) * 4096 + (2 * wave) * 512 + lane * 8;
      async16(p0 + (2 * wave) * 512, src);
      async16(p0 + (2 * wave + 1) * 512, src + 512);
    }
    #pragma unroll
    for (int ksl = 0; ksl < 4; ++ksl) {
      half8 bf0 = *(const half8*)&p1[(ksl * 2 + 0) * 512 + lane * 8];
      half8 bf1 = *(const half8*)&p1[(ksl * 2 + 1) * 512 + lane * 8];
      #pragma unroll
      for (int mi = 0; mi < 2; ++mi) {
        acc1[mi][0] = __builtin_amdgcn_mfma_f32_16x16x32_f16(af[mi][4 + ksl], bf0, acc1[mi][0], 0, 0, 0);
        acc1[mi][1] = __builtin_amdgcn_mfma_f32_16x16x32_f16(af[mi][4 + ksl], bf1, acc1[mi][1], 0, 0, 0);
      }
    }
    // epilogue1: bias + rel rank-2 + relu -> per-wave myC (fp16)
    #pragma unroll
    for (int nt = 0; nt < 2; ++nt)
      #pragma unroll
      for (int mi = 0; mi < 2; ++mi)
        #pragma unroll
        for (int r = 0; r < 4; ++r) {
          int R = wave * 32 + mi * 16 + quad * 4 + r;
          float2 rr = *(const float2*)&sh_rel[2 * R];
          float val = acc1[mi][nt][r] + ebv[nt] + rr.x * r0v[nt] + rr.y * r1v[nt];
          myC[(mi * 16 + quad * 4 + r) * 40 + nt * 16 + ln] = (_Float16)fmaxf(val, 0.f);
        }
    // GEMM2 partial-K (same wave wrote myC; lgkmcnt handles dep)
    #pragma unroll
    for (int mi = 0; mi < 2; ++mi) {
      half8 a2 = *(const half8*)&myC[(mi * 16 + ln) * 40 + quad * 8];
      #pragma unroll
      for (int nt2 = 0; nt2 < 8; ++nt2)
        acc2[mi][nt2] = __builtin_amdgcn_mfma_f32_16x16x32_f16(a2, b2f[nt2], acc2[mi][nt2], 0, 0, 0);
    }
  }

  // ---- aggregate: zero agg32, LDS atomics, normalize -> agg16 ----
  __syncthreads();                                   // p/myC reads done
  float* agg32 = (float*)uni;
  for (int i = tid; i < 8976; i += 256) agg32[i] = 0.f;
  float eb2v[8];
  #pragma unroll
  for (int t = 0; t < 8; ++t) eb2v[t] = eb2[t * 16 + ln];
  int dstv[2][4];
  float vldv[2][4];
  #pragma unroll
  for (int mi = 0; mi < 2; ++mi)
    #pragma unroll
    for (int r = 0; r < 4; ++r) {
      int e = mi * 16 + quad * 4 + r;
      dstv[mi][r] = (wave * 17 + sh_edge[2 * e]) * 132;
      vldv[mi][r] = sh_valid[wave * 32 + e];
    }
  __syncthreads();
  #pragma unroll
  for (int nt2 = 0; nt2 < 8; ++nt2) {
    int d = nt2 * 16 + ln;
    #pragma unroll
    for (int mi = 0; mi < 2; ++mi)
      #pragma unroll
      for (int r = 0; r < 4; ++r) {
        float msg = (acc2[mi][nt2][r] + eb2v[nt2]) * vldv[mi][r];
        atomicAdd(&agg32[dstv[mi][r] + d], msg);
      }
  }
  __syncthreads();
  for (int i = tid; i < 8704; i += 256) {
    int gv = i >> 7, d = i & 127;
    sh_agg16[gv * LDH + d] = (_Float16)(agg32[gv * 132 + d] / fmaxf(sh_denom[gv], 1.f));
  }
  __syncthreads();                                   // agg16 visible; uni free

  // ================= NODE PHASE =================
  {
    const _Float16* src = nw1img + (2 * wave) * 512 + lane * 8;
    async16(p0 + (2 * wave) * 512, src);
    async16(p0 + (2 * wave + 1) * 512, src + 512);
  }
  const int Rn = wave * 16 + ln;                     // < 64, always valid
  half8 afn0[8];
  #pragma unroll
  for (int ks = 0; ks < 8; ++ks)
    afn0[ks] = (ks < 4)
        ? *(const half8*)&sh_h16[Rn * LDH + ks * 32 + quad * 8]
        : *(const half8*)&sh_agg16[Rn * LDH + (ks - 4) * 32 + quad * 8];
  half8 afn1[8];                                     // wave 0: tile 4 (rows 64..67)
  if (wave == 0) {
    const int Rx = (64 + ln < 68) ? 64 + ln : 67;
    #pragma unroll
    for (int ks = 0; ks < 8; ++ks)
      afn1[ks] = (ks < 4)
          ? *(const half8*)&sh_h16[Rx * LDH + ks * 32 + quad * 8]
          : *(const half8*)&sh_agg16[Rx * LDH + (ks - 4) * 32 + quad * 8];
  }

  f32x4 acc4a[8], acc4b[8];
  #pragma unroll
  for (int j = 0; j < 8; ++j) { acc4a[j] = vzero; acc4b[j] = vzero; }

  for (int nc = 0; nc < 8; ++nc) {
    __syncthreads();
    {
      const _Float16* src = nw1img + (size_t)(2 * nc + 1) * 4096 + (2 * wave) * 512 + lane * 8;
      async16(p1 + (2 * wave) * 512, src);
      async16(p1 + (2 * wave + 1) * 512, src + 512);
    }
    half8 b2n[8];
    #pragma unroll
    for (int t = 0; t < 8; ++t)
      b2n[t] = *(const half8*)(nw2img + nc * 4096 + t * 512 + lane * 8);
    float nbv[2];
    #pragma unroll
    for (int nt = 0; nt < 2; ++nt) nbv[nt] = nb1[nc * 32 + nt * 16 + ln];

    f32x4 acc3a[2], acc3b[2];
    acc3a[0] = vzero; acc3a[1] = vzero; acc3b[0] = vzero; acc3b[1] = vzero;

    #pragma unroll
    for (int ksl = 0; ksl < 4; ++ksl) {
      half8 bf0 = *(const half8*)&p0[(ksl * 2 + 0) * 512 + lane * 8];
      half8 bf1 = *(const half8*)&p0[(ksl * 2 + 1) * 512 + lane * 8];
      acc3a[0] = __builtin_amdgcn_mfma_f32_16x16x32_f16(afn0[ksl], bf0, acc3a[0], 0, 0, 0);
      acc3a[1] = __builtin_amdgcn_mfma_f32_16x16x32_f16(afn0[ksl], bf1, acc3a[1], 0, 0, 0);
      if (wave == 0) {
        acc3b[0] = __builtin_amdgcn_mfma_f32_16x16x32_f16(afn1[ksl], bf0, acc3b[0], 0, 0, 0);
        acc3b[1] = __builtin_amdgcn_mfma_f32_16x16x32_f16(afn1[ksl], bf1, acc3b[1], 0, 0, 0);
      }
    }
    __syncthreads();
    if (nc < 7) {
      const _Float16* src = nw1img + (size_t)(2 * nc + 2) * 4096 + (2 * wave) * 512 + lane * 8;
      async16(p0 + (2 * wave) * 512, src);
      async16(p0 + (2 * wave + 1) * 512, src + 512);
    }
    #pragma unroll
    for (int ksl = 0; ksl < 4; ++ksl) {
      half8 bf0 = *(const half8*)&p1[(ksl * 2 + 0) * 512 + lane * 8];
      half8 bf1 = *(const half8*)&p1[(ksl * 2 + 1) * 512 + lane * 8];
      acc3a[0] = __builtin_amdgcn_mfma_f32_16x16x32_f16(afn0[4 + ksl], bf0, acc3a[0], 0, 0, 0);
      acc3a[1] = __builtin_amdgcn_mfma_f32_16x16x32_f16(afn0[4 + ksl], bf1, acc3a[1], 0, 0, 0);
      if (wave == 0) {
        acc3b[0] = __builtin_amdgcn_mfma_f32_16x16x32_f16(afn1[4 + ksl], bf0, acc3b[0], 0, 0, 0);
        acc3b[1] = __builtin_amdgcn_mfma_f32_16x16x32_f16(afn1[4 + ksl], bf1, acc3b[1], 0, 0, 0);
      }
    }
    // relu -> myC, then GEMM4 partial-K
    #pragma unroll
    for (int nt = 0; nt < 2; ++nt)
      #pragma unroll
      for (int r = 0; r < 4; ++r)
        myC[(quad * 4 + r) * 40 + nt * 16 + ln] = (_Float16)fmaxf(acc3a[nt][r] + nbv[nt], 0.f);
    if (wave == 0) {
      #pragma unroll
      for (int nt = 0; nt < 2; ++nt)
        #pragma unroll
        for (int r = 0; r < 4; ++r)
          myC[(16 + quad * 4 + r) * 40 + nt * 16 + ln] = (_Float16)fmaxf(acc3b[nt][r] + nbv[nt], 0.f);
    }
    {
      half8 a2 = *(const half8*)&myC[ln * 40 + quad * 8];
      #pragma unroll
      for (int nt2 = 0; nt2 < 8; ++nt2)
        acc4a[nt2] = __builtin_amdgcn_mfma_f32_16x16x32_f16(a2, b2n[nt2], acc4a[nt2], 0, 0, 0);
    }
    if (wave == 0) {
      half8 a2b = *(const half8*)&myC[(16 + ln) * 40 + quad * 8];
      #pragma unroll
      for (int nt2 = 0; nt2 < 8; ++nt2)
        acc4b[nt2] = __builtin_amdgcn_mfma_f32_16x16x32_f16(a2b, b2n[nt2], acc4b[nt2], 0, 0, 0);
    }
  }

  // ---- final epilogue: residual + LayerNorm + mask -> ost -> coalesced store ---
  float gam[8], bet[8], nb2v[8];
  #pragma unroll
  for (int nt2 = 0; nt2 < 8; ++nt2) {
    int d = nt2 * 16 + ln;
    gam[nt2] = gamma[d]; bet[nt2] = beta[d]; nb2v[nt2] = nb2[d];
  }
  __syncthreads();                                   // node LDS reads done; uni -> ost
  float* ost = (float*)uni;
  {
    float xv[8][4];
    #pragma unroll
    for (int nt2 = 0; nt2 < 8; ++nt2) {
      int d = nt2 * 16 + ln;
      #pragma unroll
      for (int r = 0; r < 4; ++r) {
        int R = wave * 16 + quad * 4 + r;
        xv[nt2][r] = (float)sh_h16[R * LDH + d] + (acc4a[nt2][r] + nb2v[nt2]) * sh_hasn[R];
      }
    }
    #pragma unroll
    for (int r = 0; r < 4; ++r) {
      float s = 0.f, s2 = 0.f;
      #pragma unroll
      for (int nt2 = 0; nt2 < 8; ++nt2) { float x = xv[nt2][r]; s += x; s2 += x * x; }
      #pragma unroll
      for (int m = 1; m < 16; m <<= 1) { s += __shfl_xor(s, m, 64); s2 += __shfl_xor(s2, m, 64); }
      float mu = s * (1.f / 128.f);
      float var = s2 * (1.f / 128.f) - mu * mu;
      float rstd = rsqrtf(var + 1e-5f);
      int R = wave * 16 + quad * 4 + r;
      float mk = sh_maskf[R];
      #pragma unroll
      for (int nt2 = 0; nt2 < 8; ++nt2) {
        int d = nt2 * 16 + ln;
        ost[R * 132 + d] = ((xv[nt2][r] - mu) * rstd * gam[nt2] + bet[nt2]) * mk;
      }
    }
  }
  if (wave == 0) {                                   // tile 4: rows 64..67
    float xv[8][4];
    #pragma unroll
    for (int nt2 = 0; nt2 < 8; ++nt2) {
      int d = nt2 * 16 + ln;
      #pragma unroll
      for (int r = 0; r < 4; ++r) {
        int R = 64 + quad * 4 + r;
        int Rc = R < 68 ? R : 67;
        xv[nt2][r] = (float)sh_h16[Rc * LDH + d] + (acc4b[nt2][r] + nb2v[nt2]) * sh_hasn[Rc];
      }
    }
    #pragma unroll
    for (int r = 0; r < 4; ++r) {
      float s = 0.f, s2 = 0.f;
      #pragma unroll
      for (int nt2 = 0; nt2 < 8; ++nt2) { float x = xv[nt2][r]; s += x; s2 += x * x; }
      #pragma unroll
      for (int m = 1; m < 16; m <<= 1) { s += __shfl_xor(s, m, 64); s2 += __shfl_xor(s2, m, 64); }
      float mu = s * (1.f / 128.f);
      float var = s2 * (1.f / 128.f) - mu * mu;
      float rstd = rsqrtf(var + 1e-5f);
      int R = 64 + quad * 4 + r;
      if (R < 68) {
        float mk = sh_maskf[R];
        #pragma unroll
        for (int nt2 = 0; nt2 < 8; ++nt2) {
          int d = nt2 * 16 + ln;
          ost[R * 132 + d] = ((xv[nt2][r] - mu) * rstd * gam[nt2] + bet[nt2]) * mk;
        }
      }
    }
  }
  __syncthreads();
  for (int i = tid; i < 8704; i += 256)
    out[hbase + i] = ost[(i >> 7) * 132 + (i & 127)];
}

extern "C" void kernel_launch(void* const* d_in, const int* in_sizes, int n_in,
                              void* d_out, int out_size, void* d_ws, size_t ws_size,
                              hipStream_t stream) {
  const float* h     = (const float*)d_in[0];
  const float* xy    = (const float*)d_in[1];
  const int*   jm    = (const int*)d_in[2];
  const int*   ei    = (const int*)d_in[3];
  const float* ew1   = (const float*)d_in[4];
  const float* eb1   = (const float*)d_in[5];
  const float* ew2   = (const float*)d_in[6];
  const float* eb2   = (const float*)d_in[7];
  const float* nw1   = (const float*)d_in[8];
  const float* nb1   = (const float*)d_in[9];
  const float* nw2   = (const float*)d_in[10];
  const float* nb2   = (const float*)d_in[11];
  const float* gamma = (const float*)d_in[12];
  const float* beta  = (const float*)d_in[13];
  _Float16* wz = (_Float16*)d_ws;

  prep_weights<<<768, 256, 0, stream>>>(ew1, ew2, nw1, nw2, wz);
  fused_graph_layer<<<4096, 256, 0, stream>>>(h, xy, jm, ei, ew1, eb1, eb2,
                                              nb1, nb2, gamma, beta, wz,
                                              (float*)d_out);
}